// Round 2
// baseline (3556.993 us; speedup 1.0000x reference)
//
#include <hip/hip_runtime.h>
#include <stdint.h>

// IntegratedNCA: 64 steps of a neural cellular automaton.
// B=8, CH=16, H=W=96, HID=128, WDIM=128, steps=64 (hard-coded; graph capture
// requires identical launch sequence every call anyway).
//
// PRNG: JAX threefry with jax_threefry_partitionable=True (modern default):
//   split: key[i]   = threefry2x32(k0,k1, 0, i)          -> (o0,o1) pair
//   bits : bits[p]  = o0 ^ o1, (o0,o1)=threefry2x32(key, 0, p), p = flat idx
//   uniform<0.5  <=>  bits>>31 == 0

#define CHN 16
#define HIDN 128
#define WD 128
#define NB 8
#define NH 96
#define NW 96
#define NSTEPS 64
#define TS 16
#define PLANE (NH*NW)          // 9216
#define ASIZE (NB*PLANE)       // 73728 (alpha elements)

__device__ __forceinline__ uint32_t rotl(uint32_t v, int d){ return (v<<d)|(v>>(32-d)); }

// Exact JAX threefry2x32 (jax/_src/prng.py). key=(k0,k1), ctr=(x0,x1).
__device__ __forceinline__ void threefry2x32(uint32_t k0, uint32_t k1,
                                             uint32_t x0, uint32_t x1,
                                             uint32_t &o0, uint32_t &o1){
  uint32_t k2 = k0 ^ k1 ^ 0x1BD11BDAu;
  x0 += k0; x1 += k1;
  x0 += x1; x1 = rotl(x1,13); x1 ^= x0;
  x0 += x1; x1 = rotl(x1,15); x1 ^= x0;
  x0 += x1; x1 = rotl(x1,26); x1 ^= x0;
  x0 += x1; x1 = rotl(x1, 6); x1 ^= x0;
  x0 += k1; x1 += k2 + 1u;
  x0 += x1; x1 = rotl(x1,17); x1 ^= x0;
  x0 += x1; x1 = rotl(x1,29); x1 ^= x0;
  x0 += x1; x1 = rotl(x1,16); x1 ^= x0;
  x0 += x1; x1 = rotl(x1,24); x1 ^= x0;
  x0 += k2; x1 += k0 + 2u;
  x0 += x1; x1 = rotl(x1,13); x1 ^= x0;
  x0 += x1; x1 = rotl(x1,15); x1 ^= x0;
  x0 += x1; x1 = rotl(x1,26); x1 ^= x0;
  x0 += x1; x1 = rotl(x1, 6); x1 ^= x0;
  x0 += k0; x1 += k1 + 3u;
  x0 += x1; x1 = rotl(x1,17); x1 ^= x0;
  x0 += x1; x1 = rotl(x1,29); x1 ^= x0;
  x0 += x1; x1 = rotl(x1,16); x1 ^= x0;
  x0 += x1; x1 = rotl(x1,24); x1 ^= x0;
  x0 += k1; x1 += k2 + 4u;
  x0 += x1; x1 = rotl(x1,13); x1 ^= x0;
  x0 += x1; x1 = rotl(x1,15); x1 ^= x0;
  x0 += x1; x1 = rotl(x1,26); x1 ^= x0;
  x0 += x1; x1 = rotl(x1, 6); x1 ^= x0;
  x0 += k2; x1 += k0 + 5u;
  o0 = x0; o1 = x1;
}

// Precompute (runs once per call; ws is re-poisoned before every timed launch):
//  w1eff[128][32]: cols 0..15 = W1[:, :16]; cols 16..31 = W1[:,16+2c]+W1[:,17+2c]
//                  (grouped conv duplicates perception channel pairs -> fold)
//  w2t[128][16]  : W2 transposed
//  c1[8][128]    : b1 + W1[:,48:176] . w[b]   (w_exp is constant per batch)
//  keys[64][2]   : jax.random.split(key(42), 64), partitionable/foldlike
__global__ __launch_bounds__(256) void nca_pre(
    const float* __restrict__ w, const float* __restrict__ W1,
    const float* __restrict__ b1, const float* __restrict__ W2,
    float* __restrict__ w1eff, float* __restrict__ w2t,
    float* __restrict__ c1, uint32_t* __restrict__ keys)
{
  const int t = threadIdx.x;
  for (int idx = t; idx < HIDN*32; idx += 256){
    int n = idx >> 5, k = idx & 31;
    float v;
    if (k < 16) v = W1[n*176 + k];
    else { int cc = k - 16; v = W1[n*176 + 16 + 2*cc] + W1[n*176 + 17 + 2*cc]; }
    w1eff[idx] = v;
  }
  for (int idx = t; idx < HIDN*CHN; idx += 256){
    int n = idx >> 4, cc = idx & 15;
    w2t[idx] = W2[cc*HIDN + n];
  }
  for (int idx = t; idx < NB*HIDN; idx += 256){
    int b = idx >> 7, n = idx & 127;
    float s = b1[n];
    for (int k = 0; k < WD; ++k) s = fmaf(W1[n*176 + 48 + k], w[b*WD + k], s);
    c1[idx] = s;
  }
  if (t < NSTEPS){
    // foldlike split: key[i] = both words of threefry(0,42, hi=0, lo=i)
    uint32_t o0, o1;
    threefry2x32(0u, 42u, 0u, (uint32_t)t, o0, o1);
    keys[2*t]   = o0;
    keys[2*t+1] = o1;
  }
}

// Phase A: per 16x16 tile: stage x(+halo) in LDS, compute perception (folded),
// h = relu(W1x*xc + W1p*pc + c1), delta = W2.h, threefry update mask,
// Y = x + delta*upd, M = pre_life(old alpha).
__global__ __launch_bounds__(256) void nca_step_a(
    const float* __restrict__ X, const float* __restrict__ w1eff,
    const float* __restrict__ w2t, const float* __restrict__ c1,
    const uint32_t* __restrict__ keys, int step,
    float* __restrict__ Y, unsigned char* __restrict__ M)
{
  __shared__ float xs[CHN][TS+2][TS+2];
  const int bz = blockIdx.z;
  const int gh0 = blockIdx.y * TS, gw0 = blockIdx.x * TS;
  const int tid = threadIdx.x;

  // stage tile with halo=1; zero-pad OOB (exact for SAME conv; safe for >0.1 maxpool)
  for (int idx = tid; idx < CHN*(TS+2)*(TS+2); idx += 256){
    int ch  = idx / ((TS+2)*(TS+2));
    int rem = idx % ((TS+2)*(TS+2));
    int hh = rem / (TS+2), ww = rem % (TS+2);
    int gh = gh0 + hh - 1, gw = gw0 + ww - 1;
    float v = 0.f;
    if (gh >= 0 && gh < NH && gw >= 0 && gw < NW)
      v = X[((bz*CHN + ch)*NH + gh)*NW + gw];
    xs[ch][hh][ww] = v;
  }
  __syncthreads();

  const int r = tid >> 4, c = tid & 15;
  const int gh = gh0 + r, gw = gw0 + c;

  float xc[CHN], pc[CHN];
  #pragma unroll
  for (int ch = 0; ch < CHN; ++ch) xc[ch] = xs[ch][r+1][c+1];
  // grouped conv: channels 0..7 -> sx, 8..15 -> sy (cross-correlation, no flip)
  #pragma unroll
  for (int ch = 0; ch < 8; ++ch){
    pc[ch] =      (xs[ch][r  ][c+2] - xs[ch][r  ][c  ])
           + 2.f*(xs[ch][r+1][c+2] - xs[ch][r+1][c  ])
           +     (xs[ch][r+2][c+2] - xs[ch][r+2][c  ]);
  }
  #pragma unroll
  for (int ch = 8; ch < 16; ++ch){
    pc[ch] =      (xs[ch][r+2][c  ] - xs[ch][r  ][c  ])
           + 2.f*(xs[ch][r+2][c+1] - xs[ch][r  ][c+1])
           +     (xs[ch][r+2][c+2] - xs[ch][r  ][c+2]);
  }
  // pre_life: 3x3 max of OLD alpha > 0.1
  float mx = xs[3][r][c];
  #pragma unroll
  for (int dr = 0; dr < 3; ++dr)
    #pragma unroll
    for (int dc = 0; dc < 3; ++dc)
      mx = fmaxf(mx, xs[3][r+dr][c+dc]);

  float acc[CHN];
  #pragma unroll
  for (int i = 0; i < CHN; ++i) acc[i] = 0.f;
  const float* c1b = c1 + bz*HIDN;

  #pragma unroll 4
  for (int n = 0; n < HIDN; ++n){
    const float* wr = w1eff + (n << 5);   // uniform address -> scalar loads
    float h0 = c1b[n], h1 = 0.f, h2 = 0.f, h3 = 0.f;
    #pragma unroll
    for (int k = 0; k < 8; ++k){
      h0 = fmaf(xc[k],   wr[k],    h0);
      h1 = fmaf(xc[k+8], wr[k+8],  h1);
      h2 = fmaf(pc[k],   wr[k+16], h2);
      h3 = fmaf(pc[k+8], wr[k+24], h3);
    }
    float hv = fmaxf((h0+h1)+(h2+h3), 0.f);
    const float* w2r = w2t + (n << 4);
    #pragma unroll
    for (int cc = 0; cc < CHN; ++cc) acc[cc] = fmaf(hv, w2r[cc], acc[cc]);
  }

  // stochastic update, partitionable bits: bits[p] = o0^o1, ctr=(0, p)
  int pos = bz*PLANE + gh*NW + gw;
  uint32_t o0, o1;
  threefry2x32(keys[2*step], keys[2*step+1], 0u, (uint32_t)pos, o0, o1);
  uint32_t bits = o0 ^ o1;
  float uf = (((bits >> 31) == 0u) && (xc[3] > 0.1f)) ? 1.f : 0.f;

  #pragma unroll
  for (int cc = 0; cc < CHN; ++cc)
    Y[((bz*CHN + cc)*NH + gh)*NW + gw] = fmaf(acc[cc], uf, xc[cc]);
  M[pos] = (mx > 0.1f) ? (unsigned char)1 : (unsigned char)0;
}

// Phase B: life = pre_life & (3x3 max of NEW alpha > 0.1); Xn = Y * life
__global__ __launch_bounds__(256) void nca_step_b(
    const float* __restrict__ Y, const unsigned char* __restrict__ M,
    float* __restrict__ Xn)
{
  __shared__ float as_[TS+2][TS+2];
  const int bz = blockIdx.z;
  const int gh0 = blockIdx.y * TS, gw0 = blockIdx.x * TS;
  const int tid = threadIdx.x;
  for (int idx = tid; idx < (TS+2)*(TS+2); idx += 256){
    int hh = idx / (TS+2), ww = idx % (TS+2);
    int gh = gh0 + hh - 1, gw = gw0 + ww - 1;
    float v = 0.f;
    if (gh >= 0 && gh < NH && gw >= 0 && gw < NW)
      v = Y[((bz*CHN + 3)*NH + gh)*NW + gw];
    as_[hh][ww] = v;
  }
  __syncthreads();
  const int r = tid >> 4, c = tid & 15;
  const int gh = gh0 + r, gw = gw0 + c;
  float mx = as_[r][c];
  #pragma unroll
  for (int dr = 0; dr < 3; ++dr)
    #pragma unroll
    for (int dc = 0; dc < 3; ++dc)
      mx = fmaxf(mx, as_[r+dr][c+dc]);
  int pos = bz*PLANE + gh*NW + gw;
  float lf = (M[pos] && (mx > 0.1f)) ? 1.f : 0.f;
  #pragma unroll
  for (int cc = 0; cc < CHN; ++cc){
    int o = ((bz*CHN + cc)*NH + gh)*NW + gw;
    Xn[o] = Y[o] * lf;
  }
}

extern "C" void kernel_launch(void* const* d_in, const int* in_sizes, int n_in,
                              void* d_out, int out_size, void* d_ws, size_t ws_size,
                              hipStream_t stream) {
  const float* x  = (const float*)d_in[0];
  const float* w  = (const float*)d_in[1];
  // d_in[2] = sobel (hard-coded), d_in[6] = steps (=64, hard-coded)
  const float* W1 = (const float*)d_in[3];
  const float* b1 = (const float*)d_in[4];
  const float* W2 = (const float*)d_in[5];
  float* out = (float*)d_out;
  char* ws = (char*)d_ws;

  size_t off = 0;
  float*    w1eff = (float*)(ws + off);    off += (size_t)HIDN*32*4;       // 16384
  float*    w2t   = (float*)(ws + off);    off += (size_t)HIDN*CHN*4;      // 8192
  float*    c1    = (float*)(ws + off);    off += (size_t)NB*HIDN*4;       // 4096
  uint32_t* keys  = (uint32_t*)(ws + off); off += (size_t)NSTEPS*2*4;      // 512
  unsigned char* M = (unsigned char*)(ws + off); off += (size_t)ASIZE;     // 73728
  float*    Xbuf  = (float*)(ws + off);    off += (size_t)NB*CHN*PLANE*4;  // 4.7 MB
  float*    Ybuf  = (float*)(ws + off);    off += (size_t)NB*CHN*PLANE*4;  // 4.7 MB
  (void)ws_size; (void)in_sizes; (void)n_in; (void)out_size;

  nca_pre<<<dim3(1), dim3(256), 0, stream>>>(w, W1, b1, W2, w1eff, w2t, c1, keys);

  dim3 grid(NW/TS, NH/TS, NB), blk(256);
  const float* src = x;
  for (int s = 0; s < NSTEPS; ++s){
    float* dst = (s & 1) ? out : Xbuf;   // s=63 (last) lands in d_out
    nca_step_a<<<grid, blk, 0, stream>>>(src, w1eff, w2t, c1, keys, s, Ybuf, M);
    nca_step_b<<<grid, blk, 0, stream>>>(Ybuf, M, dst);
    src = dst;
  }
}

// Round 5
// 2641.339 us; speedup vs baseline: 1.3467x; 1.3467x over previous
//
#include <hip/hip_runtime.h>
#include <stdint.h>

// IntegratedNCA: 64 NCA steps. B=8, CH=16, H=W=96, HID=128, WDIM=128.
// Multi-launch structure (per-step kernel = the global sync). Phase B (life
// masking) is fused into the NEXT step's staging: X_s = Y_{s-1} * life_{s-1}
// reconstructed in LDS from Y (alpha staged with halo 2) and M.
//
// PRNG: JAX threefry, jax_threefry_partitionable=True (verified green in R2):
//   split: key[i]  = threefry2x32(0,42, 0, i)   (computed on HOST, passed as args)
//   bits : bits[p] = o0^o1, (o0,o1)=threefry2x32(key, 0, p); uniform<0.5 <=> bits>>31==0

#define CHN 16
#define HIDN 128
#define WD 128
#define NB 8
#define NH 96
#define NW 96
#define NSTEPS 64
#define TW 16
#define TH 8
#define PLANE (NH*NW)          // 9216
#define TILES_X (NW/TW)        // 6
#define TILES_Y (NH/TH)        // 12
#define TPI (TILES_X*TILES_Y)  // 72
#define NBLK (NB*TPI)          // 576
#define HW_ (TH+2)             // 10 staged rows (halo 1)
#define WW_ (TW+2)             // 18 staged cols (halo 1)

__host__ __device__ __forceinline__ uint32_t rotl(uint32_t v, int d){ return (v<<d)|(v>>(32-d)); }

__host__ __device__ __forceinline__ void threefry2x32(uint32_t k0, uint32_t k1,
                                                      uint32_t x0, uint32_t x1,
                                                      uint32_t &o0, uint32_t &o1){
  uint32_t k2 = k0 ^ k1 ^ 0x1BD11BDAu;
  x0 += k0; x1 += k1;
  x0 += x1; x1 = rotl(x1,13); x1 ^= x0;
  x0 += x1; x1 = rotl(x1,15); x1 ^= x0;
  x0 += x1; x1 = rotl(x1,26); x1 ^= x0;
  x0 += x1; x1 = rotl(x1, 6); x1 ^= x0;
  x0 += k1; x1 += k2 + 1u;
  x0 += x1; x1 = rotl(x1,17); x1 ^= x0;
  x0 += x1; x1 = rotl(x1,29); x1 ^= x0;
  x0 += x1; x1 = rotl(x1,16); x1 ^= x0;
  x0 += x1; x1 = rotl(x1,24); x1 ^= x0;
  x0 += k2; x1 += k0 + 2u;
  x0 += x1; x1 = rotl(x1,13); x1 ^= x0;
  x0 += x1; x1 = rotl(x1,15); x1 ^= x0;
  x0 += x1; x1 = rotl(x1,26); x1 ^= x0;
  x0 += x1; x1 = rotl(x1, 6); x1 ^= x0;
  x0 += k0; x1 += k1 + 3u;
  x0 += x1; x1 = rotl(x1,17); x1 ^= x0;
  x0 += x1; x1 = rotl(x1,29); x1 ^= x0;
  x0 += x1; x1 = rotl(x1,16); x1 ^= x0;
  x0 += x1; x1 = rotl(x1,24); x1 ^= x0;
  x0 += k1; x1 += k2 + 4u;
  x0 += x1; x1 = rotl(x1,13); x1 ^= x0;
  x0 += x1; x1 = rotl(x1,15); x1 ^= x0;
  x0 += x1; x1 = rotl(x1,26); x1 ^= x0;
  x0 += x1; x1 = rotl(x1, 6); x1 ^= x0;
  x0 += k2; x1 += k0 + 5u;
  o0 = x0; o1 = x1;
}

// Pre: w1eff[128][32] (cols 0..15 = W1[:, :16]; 16..31 folded perception pairs,
// since grouped conv duplicates channel pairs), w2t[128][16] = W2^T,
// c1[8][128] = b1 + W1[:,48:176].w[b]  (w_exp constant per batch).
// Grid = 8 blocks (one per batch); block 0 additionally writes w1eff/w2t.
__global__ __launch_bounds__(256) void nca_pre(
    const float* __restrict__ w, const float* __restrict__ W1,
    const float* __restrict__ b1, const float* __restrict__ W2,
    float* __restrict__ w1eff, float* __restrict__ w2t, float* __restrict__ c1)
{
  const int b = blockIdx.x, t = threadIdx.x;
  if (b == 0){
    for (int idx = t; idx < HIDN*32; idx += 256){
      int n = idx >> 5, k = idx & 31;
      float v;
      if (k < 16) v = W1[n*176 + k];
      else { int cc = k - 16; v = W1[n*176 + 16 + 2*cc] + W1[n*176 + 17 + 2*cc]; }
      w1eff[idx] = v;
    }
    for (int idx = t; idx < HIDN*CHN; idx += 256){
      int n = idx >> 4, cc = idx & 15;
      w2t[idx] = W2[cc*HIDN + n];
    }
  }
  if (t < HIDN){
    float s = b1[t];
    const float* wrow = W1 + t*176 + 48;
    const float* wb = w + b*WD;
    #pragma unroll 8
    for (int k = 0; k < WD; ++k) s = fmaf(wrow[k], wb[k], s);
    c1[b*HIDN + t] = s;
  }
}

// One NCA step, fused. Block = 8x16 pixel tile x 2 hidden halves (256 thr).
// FIRST: X = input x. Else: X = Yp * (Mp & living(Yp alpha)) built in LDS.
template<bool FIRST>
__global__ __launch_bounds__(256) void nca_step(
    const float* __restrict__ Xin,          // x if FIRST, else Y_{s-1}
    const unsigned char* __restrict__ Mp,   // M_{s-1} (ignored if FIRST)
    const float* __restrict__ w1eff, const float* __restrict__ w2t,
    const float* __restrict__ c1,
    uint32_t key0, uint32_t key1,
    float* __restrict__ Yn, unsigned char* __restrict__ Mn)
{
  __shared__ float xs[CHN][HW_][WW_];   // 11520 B: X tile + halo 1
  __shared__ float ya[HW_+2][WW_+2];    //   960 B: Y alpha + halo 2
  __shared__ float lifes[HW_][WW_];     //   720 B
  __shared__ float red[TH*TW][17];      //  8704 B: hidden-split partials

  const int T = blockIdx.x;
  const int b = T / TPI, t = T % TPI;
  const int tw0 = (t % TILES_X)*TW, th0 = (t / TILES_X)*TH;
  const int tid = threadIdx.x;

  if (FIRST){
    for (int idx = tid; idx < CHN*HW_*WW_; idx += 256){
      int ch = idx / (HW_*WW_), rem = idx % (HW_*WW_);
      int hh = rem / WW_, ww = rem % WW_;
      int g2 = th0 - 1 + hh, w2 = tw0 - 1 + ww;
      float v = 0.f;
      if ((unsigned)g2 < NH && (unsigned)w2 < NW)
        v = Xin[((b*CHN + ch)*NH + g2)*NW + w2];
      xs[ch][hh][ww] = v;
    }
  } else {
    // Y alpha with halo 2 (zero-pad OOB: 0 <= 0.1 never flips the mask)
    for (int idx = tid; idx < (HW_+2)*(WW_+2); idx += 256){
      int hh = idx / (WW_+2), ww = idx % (WW_+2);
      int g2 = th0 - 2 + hh, w2 = tw0 - 2 + ww;
      float v = 0.f;
      if ((unsigned)g2 < NH && (unsigned)w2 < NW)
        v = Xin[((b*CHN + 3)*NH + g2)*NW + w2];
      ya[hh][ww] = v;
    }
    __syncthreads();
    // life over tile + halo 1
    for (int idx = tid; idx < HW_*WW_; idx += 256){
      int hh = idx / WW_, ww = idx % WW_;
      int g2 = th0 - 1 + hh, w2 = tw0 - 1 + ww;
      float lf = 0.f;
      if ((unsigned)g2 < NH && (unsigned)w2 < NW){
        float mx = ya[hh][ww];
        #pragma unroll
        for (int dr = 0; dr < 3; ++dr)
          #pragma unroll
          for (int dc = 0; dc < 3; ++dc)
            mx = fmaxf(mx, ya[hh+dr][ww+dc]);
        lf = (Mp[b*PLANE + g2*NW + w2] && (mx > 0.1f)) ? 1.f : 0.f;
      }
      lifes[hh][ww] = lf;
    }
    __syncthreads();
    // X = Y * life
    for (int idx = tid; idx < CHN*HW_*WW_; idx += 256){
      int ch = idx / (HW_*WW_), rem = idx % (HW_*WW_);
      int hh = rem / WW_, ww = rem % WW_;
      int g2 = th0 - 1 + hh, w2 = tw0 - 1 + ww;
      float v = 0.f;
      if ((unsigned)g2 < NH && (unsigned)w2 < NW)
        v = Xin[((b*CHN + ch)*NH + g2)*NW + w2] * lifes[hh][ww];
      xs[ch][hh][ww] = v;
    }
  }
  __syncthreads();

  const int px = tid & 127, half = tid >> 7;
  const int c = px & 15, r = px >> 4;
  const int gh = th0 + r, gw = tw0 + c;
  const int pos = b*PLANE + gh*NW + gw;

  float xc[CHN], pc[CHN];
  #pragma unroll
  for (int ch = 0; ch < CHN; ++ch) xc[ch] = xs[ch][r+1][c+1];
  // grouped conv: out ch 0..7 -> sx, 8..15 -> sy (cross-correlation)
  #pragma unroll
  for (int ch = 0; ch < 8; ++ch){
    pc[ch] =      (xs[ch][r  ][c+2] - xs[ch][r  ][c  ])
           + 2.f*(xs[ch][r+1][c+2] - xs[ch][r+1][c  ])
           +     (xs[ch][r+2][c+2] - xs[ch][r+2][c  ]);
  }
  #pragma unroll
  for (int ch = 8; ch < 16; ++ch){
    pc[ch] =      (xs[ch][r+2][c  ] - xs[ch][r  ][c  ])
           + 2.f*(xs[ch][r+2][c+1] - xs[ch][r  ][c+1])
           +     (xs[ch][r+2][c+2] - xs[ch][r  ][c+2]);
  }
  float mx = xs[3][r][c];
  #pragma unroll
  for (int dr = 0; dr < 3; ++dr)
    #pragma unroll
    for (int dc = 0; dc < 3; ++dc)
      mx = fmaxf(mx, xs[3][r+dr][c+dc]);

  float acc[CHN];
  #pragma unroll
  for (int i = 0; i < CHN; ++i) acc[i] = 0.f;
  // readfirstlane: half is wave-uniform; force SGPR so weight addresses stay
  // scalar (s_load path, as in the green R2 kernel where SGPR=112).
  const int nbase = __builtin_amdgcn_readfirstlane(half) << 6;
  const float* c1b = c1 + b*HIDN;

  #pragma unroll 4
  for (int nn = 0; nn < 64; ++nn){
    const int n = nbase + nn;
    const float* wr = w1eff + (n << 5);
    float h0 = c1b[n], h1 = 0.f, h2 = 0.f, h3 = 0.f;
    #pragma unroll
    for (int k = 0; k < 8; ++k){
      h0 = fmaf(xc[k],   wr[k],    h0);
      h1 = fmaf(xc[k+8], wr[k+8],  h1);
      h2 = fmaf(pc[k],   wr[k+16], h2);
      h3 = fmaf(pc[k+8], wr[k+24], h3);
    }
    float hv = fmaxf((h0+h1)+(h2+h3), 0.f);
    const float* w2r = w2t + (n << 4);
    #pragma unroll
    for (int cc = 0; cc < CHN; ++cc) acc[cc] = fmaf(hv, w2r[cc], acc[cc]);
  }

  if (half){
    #pragma unroll
    for (int cc = 0; cc < CHN; ++cc) red[px][cc] = acc[cc];
  }
  __syncthreads();
  if (!half){
    #pragma unroll
    for (int cc = 0; cc < CHN; ++cc) acc[cc] += red[px][cc];
    uint32_t o0, o1;
    threefry2x32(key0, key1, 0u, (uint32_t)pos, o0, o1);
    float uf = ((((o0 ^ o1) >> 31) == 0u) && (xc[3] > 0.1f)) ? 1.f : 0.f;
    #pragma unroll
    for (int cc = 0; cc < CHN; ++cc)
      Yn[((b*CHN + cc)*NH + gh)*NW + gw] = fmaf(acc[cc], uf, xc[cc]);
    Mn[pos] = (mx > 0.1f) ? (unsigned char)1 : (unsigned char)0;
  }
}

// Final: out = Y_63 * (M_63 & living(Y_63 alpha))
__global__ __launch_bounds__(256) void nca_final(
    const float* __restrict__ Yp, const unsigned char* __restrict__ Mp,
    float* __restrict__ out)
{
  __shared__ float ya[HW_+2][WW_+2];
  __shared__ float lifes[TH][TW];
  const int T = blockIdx.x;
  const int b = T / TPI, t = T % TPI;
  const int tw0 = (t % TILES_X)*TW, th0 = (t / TILES_X)*TH;
  const int tid = threadIdx.x;
  for (int idx = tid; idx < (HW_+2)*(WW_+2); idx += 256){
    int hh = idx / (WW_+2), ww = idx % (WW_+2);
    int g2 = th0 - 2 + hh, w2 = tw0 - 2 + ww;
    float v = 0.f;
    if ((unsigned)g2 < NH && (unsigned)w2 < NW)
      v = Yp[((b*CHN + 3)*NH + g2)*NW + w2];
    ya[hh][ww] = v;
  }
  __syncthreads();
  if (tid < TH*TW){
    int i = tid >> 4, j = tid & 15;
    float mx = ya[i+1][j+1];
    #pragma unroll
    for (int dr = 0; dr < 3; ++dr)
      #pragma unroll
      for (int dc = 0; dc < 3; ++dc)
        mx = fmaxf(mx, ya[i+1+dr][j+1+dc]);
    lifes[i][j] = (Mp[b*PLANE + (th0+i)*NW + (tw0+j)] && (mx > 0.1f)) ? 1.f : 0.f;
  }
  __syncthreads();
  for (int idx = tid; idx < CHN*TH*TW; idx += 256){
    int ch = idx >> 7, p = idx & 127;
    int i = p >> 4, j = p & 15;
    int o = ((b*CHN + ch)*NH + th0 + i)*NW + tw0 + j;
    out[o] = Yp[o] * lifes[i][j];
  }
}

extern "C" void kernel_launch(void* const* d_in, const int* in_sizes, int n_in,
                              void* d_out, int out_size, void* d_ws, size_t ws_size,
                              hipStream_t stream) {
  const float* x  = (const float*)d_in[0];
  const float* w  = (const float*)d_in[1];
  // d_in[2] = sobel (hard-coded), d_in[6] = steps (=64, hard-coded)
  const float* W1 = (const float*)d_in[3];
  const float* b1 = (const float*)d_in[4];
  const float* W2 = (const float*)d_in[5];
  float* out = (float*)d_out;
  char* ws = (char*)d_ws;

  size_t off = 0;
  float*    w1eff = (float*)(ws + off);    off += (size_t)HIDN*32*4;
  float*    w2t   = (float*)(ws + off);    off += (size_t)HIDN*CHN*4;
  float*    c1    = (float*)(ws + off);    off += (size_t)NB*HIDN*4;
  float*    Yb0   = (float*)(ws + off);    off += (size_t)NB*CHN*PLANE*4;
  float*    Yb1   = (float*)(ws + off);    off += (size_t)NB*CHN*PLANE*4;
  unsigned char* Mb0 = (unsigned char*)(ws + off); off += (size_t)NB*PLANE;
  unsigned char* Mb1 = (unsigned char*)(ws + off); off += (size_t)NB*PLANE;
  (void)ws_size; (void)in_sizes; (void)n_in; (void)out_size;

  // step keys are input-independent constants: compute on host, pass as args
  uint32_t k0[NSTEPS], k1[NSTEPS];
  for (int s = 0; s < NSTEPS; ++s) threefry2x32(0u, 42u, 0u, (uint32_t)s, k0[s], k1[s]);

  nca_pre<<<dim3(NB), dim3(256), 0, stream>>>(w, W1, b1, W2, w1eff, w2t, c1);

  nca_step<true><<<dim3(NBLK), dim3(256), 0, stream>>>(
      x, Mb1 /*unused*/, w1eff, w2t, c1, k0[0], k1[0], Yb0, Mb0);
  for (int s = 1; s < NSTEPS; ++s){
    const float* Yp = (s & 1) ? Yb0 : Yb1;
    float*       Yn = (s & 1) ? Yb1 : Yb0;
    const unsigned char* Mq = (s & 1) ? Mb0 : Mb1;
    unsigned char*       Mn = (s & 1) ? Mb1 : Mb0;
    nca_step<false><<<dim3(NBLK), dim3(256), 0, stream>>>(
        Yp, Mq, w1eff, w2t, c1, k0[s], k1[s], Yn, Mn);
  }
  // s=63 (odd) wrote Yb1/Mb1
  nca_final<<<dim3(NBLK), dim3(256), 0, stream>>>(Yb1, Mb1, out);
}

// Round 6
// 2173.979 us; speedup vs baseline: 1.6362x; 1.2150x over previous
//
#include <hip/hip_runtime.h>
#include <stdint.h>

// IntegratedNCA: 64 NCA steps. B=8, CH=16, H=W=96, HID=128, WDIM=128.
// Multi-launch (per-step kernel = the global sync). Phase B (life masking)
// fused into the NEXT step's staging: X_s = Y_{s-1} * life_{s-1} in LDS.
//
// R6: 8x8 pixel tile x hidden-split-4 (wave = one hidden quarter), 1152 blocks
// -> 18 waves/CU (was 9). Reduction via red[quarter][ch][px] (conflict-free).
//
// PRNG: JAX threefry, jax_threefry_partitionable=True (green in R2/R5):
//   split: key[i]  = threefry2x32(0,42, 0, i)   (host-side, passed as args)
//   bits : bits[p] = o0^o1, (o0,o1)=threefry2x32(key, 0, p); uniform<0.5 <=> bits>>31==0

#define CHN 16
#define HIDN 128
#define WD 128
#define NB 8
#define NH 96
#define NW 96
#define NSTEPS 64
#define TW 8
#define TH 8
#define PLANE (NH*NW)          // 9216
#define TILES_X (NW/TW)        // 12
#define TILES_Y (NH/TH)        // 12
#define TPI (TILES_X*TILES_Y)  // 144
#define NBLK (NB*TPI)          // 1152
#define HW_ (TH+2)             // 10 staged rows (halo 1)
#define WW_ (TW+2)             // 10 staged cols (halo 1)

__host__ __device__ __forceinline__ uint32_t rotl(uint32_t v, int d){ return (v<<d)|(v>>(32-d)); }

__host__ __device__ __forceinline__ void threefry2x32(uint32_t k0, uint32_t k1,
                                                      uint32_t x0, uint32_t x1,
                                                      uint32_t &o0, uint32_t &o1){
  uint32_t k2 = k0 ^ k1 ^ 0x1BD11BDAu;
  x0 += k0; x1 += k1;
  x0 += x1; x1 = rotl(x1,13); x1 ^= x0;
  x0 += x1; x1 = rotl(x1,15); x1 ^= x0;
  x0 += x1; x1 = rotl(x1,26); x1 ^= x0;
  x0 += x1; x1 = rotl(x1, 6); x1 ^= x0;
  x0 += k1; x1 += k2 + 1u;
  x0 += x1; x1 = rotl(x1,17); x1 ^= x0;
  x0 += x1; x1 = rotl(x1,29); x1 ^= x0;
  x0 += x1; x1 = rotl(x1,16); x1 ^= x0;
  x0 += x1; x1 = rotl(x1,24); x1 ^= x0;
  x0 += k2; x1 += k0 + 2u;
  x0 += x1; x1 = rotl(x1,13); x1 ^= x0;
  x0 += x1; x1 = rotl(x1,15); x1 ^= x0;
  x0 += x1; x1 = rotl(x1,26); x1 ^= x0;
  x0 += x1; x1 = rotl(x1, 6); x1 ^= x0;
  x0 += k0; x1 += k1 + 3u;
  x0 += x1; x1 = rotl(x1,17); x1 ^= x0;
  x0 += x1; x1 = rotl(x1,29); x1 ^= x0;
  x0 += x1; x1 = rotl(x1,16); x1 ^= x0;
  x0 += x1; x1 = rotl(x1,24); x1 ^= x0;
  x0 += k1; x1 += k2 + 4u;
  x0 += x1; x1 = rotl(x1,13); x1 ^= x0;
  x0 += x1; x1 = rotl(x1,15); x1 ^= x0;
  x0 += x1; x1 = rotl(x1,26); x1 ^= x0;
  x0 += x1; x1 = rotl(x1, 6); x1 ^= x0;
  x0 += k2; x1 += k0 + 5u;
  o0 = x0; o1 = x1;
}

// Pre: w1eff[128][32] (cols 0..15 = W1[:, :16]; 16..31 folded perception pairs),
// w2t[128][16] = W2^T, c1[8][128] = b1 + W1[:,48:176].w[b].
__global__ __launch_bounds__(256) void nca_pre(
    const float* __restrict__ w, const float* __restrict__ W1,
    const float* __restrict__ b1, const float* __restrict__ W2,
    float* __restrict__ w1eff, float* __restrict__ w2t, float* __restrict__ c1)
{
  const int b = blockIdx.x, t = threadIdx.x;
  if (b == 0){
    for (int idx = t; idx < HIDN*32; idx += 256){
      int n = idx >> 5, k = idx & 31;
      float v;
      if (k < 16) v = W1[n*176 + k];
      else { int cc = k - 16; v = W1[n*176 + 16 + 2*cc] + W1[n*176 + 17 + 2*cc]; }
      w1eff[idx] = v;
    }
    for (int idx = t; idx < HIDN*CHN; idx += 256){
      int n = idx >> 4, cc = idx & 15;
      w2t[idx] = W2[cc*HIDN + n];
    }
  }
  if (t < HIDN){
    float s = b1[t];
    const float* wrow = W1 + t*176 + 48;
    const float* wb = w + b*WD;
    #pragma unroll 8
    for (int k = 0; k < WD; ++k) s = fmaf(wrow[k], wb[k], s);
    c1[b*HIDN + t] = s;
  }
}

// One NCA step. Block = 8x8 pixel tile x 4 hidden quarters (256 thr, q=wave).
// FIRST: X = input x. Else: X = Yp * (Mp & living(Yp alpha)) built in LDS.
template<bool FIRST>
__global__ __launch_bounds__(256) void nca_step(
    const float* __restrict__ Xin,          // x if FIRST, else Y_{s-1}
    const unsigned char* __restrict__ Mp,   // M_{s-1} (ignored if FIRST)
    const float* __restrict__ w1eff, const float* __restrict__ w2t,
    const float* __restrict__ c1,
    uint32_t key0, uint32_t key1,
    float* __restrict__ Yn, unsigned char* __restrict__ Mn)
{
  __shared__ float xs[CHN][HW_][WW_];   //  6400 B: X tile + halo 1
  __shared__ float ya[HW_+2][WW_+2];    //   576 B: Y alpha + halo 2
  __shared__ float lifes[HW_][WW_];     //   400 B
  __shared__ float red[4][CHN][64];     // 16384 B: red[quarter][ch][px], lane=px -> conflict-free

  const int T = blockIdx.x;
  const int b = T / TPI, t = T % TPI;
  const int tw0 = (t % TILES_X)*TW, th0 = (t / TILES_X)*TH;
  const int tid = threadIdx.x;

  if (FIRST){
    for (int idx = tid; idx < CHN*HW_*WW_; idx += 256){
      int ch = idx / (HW_*WW_), rem = idx % (HW_*WW_);
      int hh = rem / WW_, ww = rem % WW_;
      int g2 = th0 - 1 + hh, w2 = tw0 - 1 + ww;
      float v = 0.f;
      if ((unsigned)g2 < NH && (unsigned)w2 < NW)
        v = Xin[((b*CHN + ch)*NH + g2)*NW + w2];
      xs[ch][hh][ww] = v;
    }
  } else {
    // Y alpha with halo 2 (zero-pad OOB: 0 <= 0.1 never flips the mask)
    for (int idx = tid; idx < (HW_+2)*(WW_+2); idx += 256){
      int hh = idx / (WW_+2), ww = idx % (WW_+2);
      int g2 = th0 - 2 + hh, w2 = tw0 - 2 + ww;
      float v = 0.f;
      if ((unsigned)g2 < NH && (unsigned)w2 < NW)
        v = Xin[((b*CHN + 3)*NH + g2)*NW + w2];
      ya[hh][ww] = v;
    }
    __syncthreads();
    // life over tile + halo 1
    for (int idx = tid; idx < HW_*WW_; idx += 256){
      int hh = idx / WW_, ww = idx % WW_;
      int g2 = th0 - 1 + hh, w2 = tw0 - 1 + ww;
      float lf = 0.f;
      if ((unsigned)g2 < NH && (unsigned)w2 < NW){
        float mx = ya[hh][ww];
        #pragma unroll
        for (int dr = 0; dr < 3; ++dr)
          #pragma unroll
          for (int dc = 0; dc < 3; ++dc)
            mx = fmaxf(mx, ya[hh+dr][ww+dc]);
        lf = (Mp[b*PLANE + g2*NW + w2] && (mx > 0.1f)) ? 1.f : 0.f;
      }
      lifes[hh][ww] = lf;
    }
    __syncthreads();
    // X = Y * life
    for (int idx = tid; idx < CHN*HW_*WW_; idx += 256){
      int ch = idx / (HW_*WW_), rem = idx % (HW_*WW_);
      int hh = rem / WW_, ww = rem % WW_;
      int g2 = th0 - 1 + hh, w2 = tw0 - 1 + ww;
      float v = 0.f;
      if ((unsigned)g2 < NH && (unsigned)w2 < NW)
        v = Xin[((b*CHN + ch)*NH + g2)*NW + w2] * lifes[hh][ww];
      xs[ch][hh][ww] = v;
    }
  }
  __syncthreads();

  const int px = tid & 63;          // pixel in 8x8 tile
  const int q  = tid >> 6;          // hidden quarter == wave id
  const int c = px & 7, r = px >> 3;
  const int gh = th0 + r, gw = tw0 + c;
  const int pos = b*PLANE + gh*NW + gw;

  float xc[CHN], pc[CHN];
  #pragma unroll
  for (int ch = 0; ch < CHN; ++ch) xc[ch] = xs[ch][r+1][c+1];
  // grouped conv: out ch 0..7 -> sx, 8..15 -> sy (cross-correlation)
  #pragma unroll
  for (int ch = 0; ch < 8; ++ch){
    pc[ch] =      (xs[ch][r  ][c+2] - xs[ch][r  ][c  ])
           + 2.f*(xs[ch][r+1][c+2] - xs[ch][r+1][c  ])
           +     (xs[ch][r+2][c+2] - xs[ch][r+2][c  ]);
  }
  #pragma unroll
  for (int ch = 8; ch < 16; ++ch){
    pc[ch] =      (xs[ch][r+2][c  ] - xs[ch][r  ][c  ])
           + 2.f*(xs[ch][r+2][c+1] - xs[ch][r  ][c+1])
           +     (xs[ch][r+2][c+2] - xs[ch][r  ][c+2]);
  }

  float acc[CHN];
  #pragma unroll
  for (int i = 0; i < CHN; ++i) acc[i] = 0.f;
  // q is wave-uniform by construction; readfirstlane keeps weight addresses
  // provably scalar (s_load path; SGPR=112 in the green R5 kernel).
  const int nbase = __builtin_amdgcn_readfirstlane(q) << 5;
  const float* c1b = c1 + b*HIDN;

  #pragma unroll 4
  for (int nn = 0; nn < 32; ++nn){
    const int n = nbase + nn;
    const float* wr = w1eff + (n << 5);
    float h0 = c1b[n], h1 = 0.f, h2 = 0.f, h3 = 0.f;
    #pragma unroll
    for (int k = 0; k < 8; ++k){
      h0 = fmaf(xc[k],   wr[k],    h0);
      h1 = fmaf(xc[k+8], wr[k+8],  h1);
      h2 = fmaf(pc[k],   wr[k+16], h2);
      h3 = fmaf(pc[k+8], wr[k+24], h3);
    }
    float hv = fmaxf((h0+h1)+(h2+h3), 0.f);
    const float* w2r = w2t + (n << 4);
    #pragma unroll
    for (int cc = 0; cc < CHN; ++cc) acc[cc] = fmaf(hv, w2r[cc], acc[cc]);
  }

  #pragma unroll
  for (int cc = 0; cc < CHN; ++cc) red[q][cc][px] = acc[cc];
  __syncthreads();

  // epilogue balanced across quarters: quarter q handles channels 4q..4q+3
  uint32_t o0, o1;
  threefry2x32(key0, key1, 0u, (uint32_t)pos, o0, o1);
  float uf = ((((o0 ^ o1) >> 31) == 0u) && (xc[3] > 0.1f)) ? 1.f : 0.f;
  #pragma unroll
  for (int cc = 0; cc < 4; ++cc){
    int ch = (q << 2) + cc;
    float v = ((red[0][ch][px] + red[1][ch][px]) +
               (red[2][ch][px] + red[3][ch][px]));
    Yn[((b*CHN + ch)*NH + gh)*NW + gw] = fmaf(v, uf, xc[ch]);
  }
  if (q == 0){  // wave-uniform branch
    float mx = xs[3][r][c];
    #pragma unroll
    for (int dr = 0; dr < 3; ++dr)
      #pragma unroll
      for (int dc = 0; dc < 3; ++dc)
        mx = fmaxf(mx, xs[3][r+dr][c+dc]);
    Mn[pos] = (mx > 0.1f) ? (unsigned char)1 : (unsigned char)0;
  }
}

// Final: out = Y_63 * (M_63 & living(Y_63 alpha))
__global__ __launch_bounds__(256) void nca_final(
    const float* __restrict__ Yp, const unsigned char* __restrict__ Mp,
    float* __restrict__ out)
{
  __shared__ float ya[HW_+2][WW_+2];
  __shared__ float lifes[TH][TW];
  const int T = blockIdx.x;
  const int b = T / TPI, t = T % TPI;
  const int tw0 = (t % TILES_X)*TW, th0 = (t / TILES_X)*TH;
  const int tid = threadIdx.x;
  for (int idx = tid; idx < (HW_+2)*(WW_+2); idx += 256){
    int hh = idx / (WW_+2), ww = idx % (WW_+2);
    int g2 = th0 - 2 + hh, w2 = tw0 - 2 + ww;
    float v = 0.f;
    if ((unsigned)g2 < NH && (unsigned)w2 < NW)
      v = Yp[((b*CHN + 3)*NH + g2)*NW + w2];
    ya[hh][ww] = v;
  }
  __syncthreads();
  if (tid < TH*TW){
    int i = tid >> 3, j = tid & 7;
    float mx = ya[i+1][j+1];
    #pragma unroll
    for (int dr = 0; dr < 3; ++dr)
      #pragma unroll
      for (int dc = 0; dc < 3; ++dc)
        mx = fmaxf(mx, ya[i+1+dr][j+1+dc]);
    lifes[i][j] = (Mp[b*PLANE + (th0+i)*NW + (tw0+j)] && (mx > 0.1f)) ? 1.f : 0.f;
  }
  __syncthreads();
  for (int idx = tid; idx < CHN*TH*TW; idx += 256){
    int ch = idx >> 6, p = idx & 63;
    int i = p >> 3, j = p & 7;
    int o = ((b*CHN + ch)*NH + th0 + i)*NW + tw0 + j;
    out[o] = Yp[o] * lifes[i][j];
  }
}

extern "C" void kernel_launch(void* const* d_in, const int* in_sizes, int n_in,
                              void* d_out, int out_size, void* d_ws, size_t ws_size,
                              hipStream_t stream) {
  const float* x  = (const float*)d_in[0];
  const float* w  = (const float*)d_in[1];
  // d_in[2] = sobel (hard-coded), d_in[6] = steps (=64, hard-coded)
  const float* W1 = (const float*)d_in[3];
  const float* b1 = (const float*)d_in[4];
  const float* W2 = (const float*)d_in[5];
  float* out = (float*)d_out;
  char* ws = (char*)d_ws;

  size_t off = 0;
  float*    w1eff = (float*)(ws + off);    off += (size_t)HIDN*32*4;
  float*    w2t   = (float*)(ws + off);    off += (size_t)HIDN*CHN*4;
  float*    c1    = (float*)(ws + off);    off += (size_t)NB*HIDN*4;
  float*    Yb0   = (float*)(ws + off);    off += (size_t)NB*CHN*PLANE*4;
  float*    Yb1   = (float*)(ws + off);    off += (size_t)NB*CHN*PLANE*4;
  unsigned char* Mb0 = (unsigned char*)(ws + off); off += (size_t)NB*PLANE;
  unsigned char* Mb1 = (unsigned char*)(ws + off); off += (size_t)NB*PLANE;
  (void)ws_size; (void)in_sizes; (void)n_in; (void)out_size;

  // step keys are input-independent constants: compute on host, pass as args
  uint32_t k0[NSTEPS], k1[NSTEPS];
  for (int s = 0; s < NSTEPS; ++s) threefry2x32(0u, 42u, 0u, (uint32_t)s, k0[s], k1[s]);

  nca_pre<<<dim3(NB), dim3(256), 0, stream>>>(w, W1, b1, W2, w1eff, w2t, c1);

  nca_step<true><<<dim3(NBLK), dim3(256), 0, stream>>>(
      x, Mb1 /*unused*/, w1eff, w2t, c1, k0[0], k1[0], Yb0, Mb0);
  for (int s = 1; s < NSTEPS; ++s){
    const float* Yp = (s & 1) ? Yb0 : Yb1;
    float*       Yn = (s & 1) ? Yb1 : Yb0;
    const unsigned char* Mq = (s & 1) ? Mb0 : Mb1;
    unsigned char*       Mn = (s & 1) ? Mb1 : Mb0;
    nca_step<false><<<dim3(NBLK), dim3(256), 0, stream>>>(
        Yp, Mq, w1eff, w2t, c1, k0[s], k1[s], Yn, Mn);
  }
  // s=63 (odd) wrote Yb1/Mb1
  nca_final<<<dim3(NBLK), dim3(256), 0, stream>>>(Yb1, Mb1, out);
}